// Round 6
// baseline (537.086 us; speedup 1.0000x reference)
//
#include <hip/hip_runtime.h>
#include <math.h>

typedef unsigned short u16;
typedef unsigned int u32;
typedef __attribute__((ext_vector_type(8))) short bf16x8_t;
typedef __attribute__((ext_vector_type(4))) float f32x4_t;
typedef __attribute__((ext_vector_type(16))) float f32x16_t;

#define S_LEN  2048
#define NH     16
#define DK     64
#define DMODEL 1024
#define MROWS  4096   // B*S
#define LOG2E  1.44269504088896f

__device__ inline u16 f2b(float f) {
  union { float f; u32 u; } c; c.f = f;
  u32 u = c.u;
  return (u16)((u + 0x7fffu + ((u >> 16) & 1u)) >> 16);  // RNE bf16
}

__device__ __forceinline__ float fexp2(float x) {
#if __has_builtin(__builtin_amdgcn_exp2f)
  return __builtin_amdgcn_exp2f(x);
#else
  return exp2f(x);
#endif
}

__device__ __forceinline__ u32 cvtpk(float lo, float hi) {
  u32 r;
  asm("v_cvt_pk_bf16_f32 %0, %1, %2" : "=v"(r) : "v"(lo), "v"(hi));
  return r;
}

// swap x's high-32-lane half with y's low-32-lane half (gfx950 v_permlane32_swap_b32)
__device__ __forceinline__ void plswap(u32 &x, u32 &y) {
  asm("v_permlane32_swap_b32 %0, %1" : "+v"(x), "+v"(y));
}

// ---------------- global -> LDS DMA: wave-uniform LDS base, lane deposits 16B at base + lane*16 ----------------
__device__ __forceinline__ void stage16(const u16* gp_lane, u16* lds_base) {
#if __has_builtin(__builtin_amdgcn_global_load_lds)
  __builtin_amdgcn_global_load_lds((const __attribute__((address_space(1))) u32*)gp_lane,
                                   (__attribute__((address_space(3))) u32*)lds_base, 16, 0, 0);
#else
  *(uint4*)(lds_base + (threadIdx.x & 63) * 8) = *(const uint4*)gp_lane;
#endif
}

// ---------------- fused prep: cast x, transpose+cast 4 weights, bias table ----------------
__global__ void prep_kernel(const float* __restrict__ x,
                            const float* __restrict__ Wq, const float* __restrict__ Wk,
                            const float* __restrict__ Wv, const float* __restrict__ Wo,
                            const float* __restrict__ rel,
                            u16* __restrict__ xb, u16* __restrict__ Wall,
                            u16* __restrict__ Wto, float* __restrict__ btab) {
  __shared__ float tile[32][33];
  const int bid = blockIdx.x, t = threadIdx.x;
  if (bid < 4096) {
    int i = (bid * 256 + t) * 4;
    float4 v = *(const float4*)(x + i);
    ushort4 o;
    o.x = f2b(v.x); o.y = f2b(v.y); o.z = f2b(v.z); o.w = f2b(v.w);
    *(ushort4*)(xb + i) = o;
  } else if (bid < 8192) {
    int bid2 = bid - 4096;
    int z = bid2 >> 10, rem = bid2 & 1023;
    const float* W; u16* Wt;
    switch (z) {
      case 0: W = Wq; Wt = Wall; break;
      case 1: W = Wk; Wt = Wall + (size_t)DMODEL * DMODEL; break;
      case 2: W = Wv; Wt = Wall + (size_t)2 * DMODEL * DMODEL; break;
      default: W = Wo; Wt = Wto; break;
    }
    int bc = (rem & 31) * 32, br = (rem >> 5) * 32;
    int tx = t & 31, ty = t >> 5;
    #pragma unroll
    for (int yy = 0; yy < 32; yy += 8)
      tile[ty + yy][tx] = W[(size_t)(br + ty + yy) * DMODEL + bc + tx];
    __syncthreads();
    #pragma unroll
    for (int yy = 0; yy < 32; yy += 8)
      Wt[(size_t)(bc + ty + yy) * DMODEL + br + tx] = f2b(tile[tx][ty + yy]);
  } else {
    // bias table: btab[h][delta+2047] = (bias(h,delta) - 16) * log2(e)   [exp2-domain]
    int idx = (bid - 8192) * 256 + t;
    if (idx < NH * 4095) {
      int h = idx / 4095;
      int dpos = idx - h * 4095;
      int delta = dpos - 2047;               // j - i; reference n = i - j
      int ret = (delta > 0) ? 16 : 0;
      int n = delta < 0 ? -delta : delta;
      int bucket;
      if (n < 8) {
        bucket = ret + n;
      } else {
        float vf = logf((float)n * 0.125f) / 2.7725887222397811f * 8.0f;
        int vil = 8 + (int)vf;
        bucket = ret + (vil < 15 ? vil : 15);
      }
      btab[idx] = (rel[bucket * NH + h] - 16.0f) * LOG2E;
    }
  }
}

// ---------------- 128x128 bf16 MFMA GEMM ----------------
#define GSTR 56   // manual-path LDS row stride (112 B): 16B-aligned, 2-way bank aliasing (free)
template <int MODE>
__global__ __launch_bounds__(256) void gemm128_kernel(const u16* __restrict__ A,
                                                      const u16* __restrict__ Bt,
                                                      float* __restrict__ C,
                                                      u16* __restrict__ q16,
                                                      u16* __restrict__ k16,
                                                      u16* __restrict__ vt16) {
  constexpr int ABSZ = (MODE == 1) ? 4608 : 128 * GSTR;
  constexpr int FSTR = (MODE == 1) ? 32 : GSTR;
  __shared__ __align__(16) u16 As[ABSZ];
  __shared__ __align__(16) u16 Bs[ABSZ];
  const int t = threadIdx.x, w = t >> 6, l = t & 63;
  const int c = l & 15, quad = l >> 4;
  const int m0 = blockIdx.x * 128, n0 = blockIdx.y * 128;
  const int wm = (w & 1) * 64, wn = (w >> 1) * 64;

  f32x4_t acc[16] = {};

  if constexpr (MODE == 1) {
    const int sr = l >> 2;
    const int k8 = (l & 3) * 8;
    const u16* Ag0 = A  + (size_t)(m0 + w * 32 + sr) * DMODEL + k8;
    const u16* Ag1 = Ag0 + (size_t)16 * DMODEL;
    const u16* Bg0 = Bt + (size_t)(n0 + w * 32 + sr) * DMODEL + k8;
    const u16* Bg1 = Bg0 + (size_t)16 * DMODEL;
    u16* Al = As + w * 1024;
    u16* Bl = Bs + w * 1024;
    for (int k0 = 0; k0 < DMODEL; k0 += 32) {
      __syncthreads();
      stage16(Ag0 + k0, Al);
      stage16(Ag1 + k0, Al + 512);
      stage16(Bg0 + k0, Bl);
      stage16(Bg1 + k0, Bl + 512);
      __syncthreads();
      bf16x8_t af[4], bfr[4];
      #pragma unroll
      for (int i = 0; i < 4; ++i) {
        af[i]  = *(const bf16x8_t*)(As + (wm + i * 16 + c) * FSTR + quad * 8);
        bfr[i] = *(const bf16x8_t*)(Bs + (wn + i * 16 + c) * FSTR + quad * 8);
      }
      #pragma unroll
      for (int mt = 0; mt < 4; ++mt)
        #pragma unroll
        for (int nt = 0; nt < 4; ++nt)
          acc[mt * 4 + nt] = __builtin_amdgcn_mfma_f32_16x16x32_bf16(af[mt], bfr[nt], acc[mt * 4 + nt], 0, 0, 0);
    }
  } else {
    const int sr = t >> 2;
    const int k8 = (t & 3) * 8;
    const u16* Ag0 = A  + (size_t)(m0 + sr) * DMODEL + k8;
    const u16* Ag1 = Ag0 + (size_t)64 * DMODEL;
    const u16* Bg0 = Bt + (size_t)(n0 + sr) * DMODEL + k8;
    const u16* Bg1 = Bg0 + (size_t)64 * DMODEL;
    u16* Al0 = As + sr * GSTR + k8;
    u16* Al1 = Al0 + 64 * GSTR;
    u16* Bl0 = Bs + sr * GSTR + k8;
    u16* Bl1 = Bl0 + 64 * GSTR;

    uint4 a0 = *(const uint4*)Ag0, a1 = *(const uint4*)Ag1;
    uint4 b0 = *(const uint4*)Bg0, b1 = *(const uint4*)Bg1;
    for (int k0 = 0; k0 < DMODEL; k0 += 32) {
      __syncthreads();
      *(uint4*)Al0 = a0; *(uint4*)Al1 = a1;
      *(uint4*)Bl0 = b0; *(uint4*)Bl1 = b1;
      __syncthreads();
      if (k0 + 32 < DMODEL) {
        a0 = *(const uint4*)(Ag0 + k0 + 32);
        a1 = *(const uint4*)(Ag1 + k0 + 32);
        b0 = *(const uint4*)(Bg0 + k0 + 32);
        b1 = *(const uint4*)(Bg1 + k0 + 32);
      }
      bf16x8_t af[4], bfr[4];
      #pragma unroll
      for (int i = 0; i < 4; ++i) {
        af[i]  = *(const bf16x8_t*)(As + (wm + i * 16 + c) * FSTR + quad * 8);
        bfr[i] = *(const bf16x8_t*)(Bs + (wn + i * 16 + c) * FSTR + quad * 8);
      }
      #pragma unroll
      for (int mt = 0; mt < 4; ++mt)
        #pragma unroll
        for (int nt = 0; nt < 4; ++nt)
          acc[mt * 4 + nt] = __builtin_amdgcn_mfma_f32_16x16x32_bf16(af[mt], bfr[nt], acc[mt * 4 + nt], 0, 0, 0);
    }
  }

  if constexpr (MODE == 0) {
    #pragma unroll
    for (int mt = 0; mt < 4; ++mt) {
      int grow0 = m0 + wm + mt * 16 + quad * 4;
      #pragma unroll
      for (int nt = 0; nt < 4; ++nt) {
        int gcol = n0 + wn + nt * 16 + c;
        #pragma unroll
        for (int r = 0; r < 4; ++r)
          C[(size_t)(grow0 + r) * DMODEL + gcol] = acc[mt * 4 + nt][r];
      }
    }
  } else {
    const int whichblk = n0 >> 10;
    if (whichblk == 2) {
      #pragma unroll
      for (int mt = 0; mt < 4; ++mt) {
        int grow0 = m0 + wm + mt * 16 + quad * 4;
        int b = grow0 >> 11, s0 = grow0 & 2047;
        #pragma unroll
        for (int nt = 0; nt < 4; ++nt) {
          int cc = (n0 + wn + nt * 16 + c) & 1023;
          int hh = cc >> 6, dk = cc & 63;
          f32x4_t v4 = acc[mt * 4 + nt];
          ushort4 o;
          o.x = f2b(v4[0]); o.y = f2b(v4[1]); o.z = f2b(v4[2]); o.w = f2b(v4[3]);
          *(ushort4*)(vt16 + (((size_t)(b * NH + hh)) * DK + dk) * S_LEN + s0) = o;
        }
      }
    } else {
      u16* tb = (w & 1) ? Bs : As;
      const int base_mw = m0 + wm;
      const int bb = base_mw >> 11, s0g = base_mw & 2047;
      const int cc = (n0 + wn) & 1023;
      const int hh = cc >> 6;
      u16* qk = (whichblk == 0 ? q16 : k16) + (((size_t)(bb * NH + hh)) * S_LEN + s0g) * DK;
      __syncthreads();
      #pragma unroll
      for (int round = 0; round < 2; ++round) {
        if ((w >> 1) == round) {
          #pragma unroll
          for (int mt = 0; mt < 4; ++mt)
            #pragma unroll
            for (int nt = 0; nt < 4; ++nt)
              #pragma unroll
              for (int r = 0; r < 4; ++r)
                tb[(mt * 16 + quad * 4 + r) * 72 + nt * 16 + c] = f2b(acc[mt * 4 + nt][r]);
          #pragma unroll
          for (int i = 0; i < 8; ++i) {
            int lrow = i * 8 + (l >> 3);
            int chk = l & 7;
            uint4 vv = *(const uint4*)(tb + lrow * 72 + chk * 8);
            *(uint4*)(qk + (size_t)lrow * DK + chk * 8) = vv;
          }
        }
        __syncthreads();
      }
    }
  }
}

// ---------------- MFMA flash attention v6: 64-q blocks x 8 waves, 4-way key-split, 4 blocks/CU ----------------
// 8 waves = 2 q-groups (32 q) x 4 key-quarters (32 keys of a 128-key tile). Grid 1024 = 4 blocks/CU
// -> occupancy cap 32 waves/CU (2x R5's 16). Per-wave inner loop byte-identical to R5 chunk-A
// (kq*32 replaces kh*64); LDS 37.9 KB x 4 = 151.5 KB fits; VGPR target 64 (= R5 measured) via
// __launch_bounds__(512,8). Epilogue: 2-round LDS tree over 4 key-quarters, aliased into dead K/V.
#define KSTR 72    // K row stride in u16 (144 B): conflict-free frag reads (R3-proven)
#define VSTR 136   // V^T row stride in u16 (272 B): same 16B-shift-per-row class
__global__ __launch_bounds__(512, 8) void attn_mfma_kernel(const u16* __restrict__ q,
                                                           const u16* __restrict__ k,
                                                           const u16* __restrict__ vt,
                                                           const float* __restrict__ btab,
                                                           u16* __restrict__ ctx) {
  __shared__ __align__(16) char smem[37888];
  u16*   Ks   = (u16*)smem;                   // [128][KSTR]  18432 B
  u16*   Vts  = (u16*)(smem + 18432);         // [64][VSTR]   17408 B
  float* band = (float*)(smem + 35840);       // [256]         1024 B
  float* lpx  = (float*)(smem + 36864);       // [2][4][32]    1024 B

  const int t = threadIdx.x;
  const int w = t >> 6, l = t & 63;
  const int c32 = l & 31, h32 = l >> 5;
  const int grp = w >> 2, kq = w & 3;

  // bijective XCD swizzle (1024 % 8 == 0): each XCD gets 128 consecutive swz = 4 bh
  const int orig = blockIdx.x;                 // 0..1023
  const int swz = (orig & 7) * 128 + (orig >> 3);
  const int bh = swz >> 5;                     // 0..31
  const int q0 = (swz & 31) * 64;
  const int h = bh & (NH - 1), b = bh >> 4;

  const u16* qb = q + (size_t)bh * S_LEN * DK;
  const u16* kb = k + (size_t)bh * S_LEN * DK;
  const u16* vb = vt + (size_t)bh * DK * S_LEN;
  const float* btp = btab + h * 4095 + (2047 - 127 - q0);

  // Q fragments (B operand of 32x32x16): lane holds Q[q = c32][dk = kb4*16 + h32*8 + j]
  bf16x8_t qfrag[4];
  {
    const u16* qp = qb + (size_t)(q0 + grp * 32 + c32) * DK + h32 * 8;
    qfrag[0] = *(const bf16x8_t*)(qp);
    qfrag[1] = *(const bf16x8_t*)(qp + 16);
    qfrag[2] = *(const bf16x8_t*)(qp + 32);
    qfrag[3] = *(const bf16x8_t*)(qp + 48);
  }

  float lp = 0.f;
  f32x16_t O0 = {}, O1 = {};   // O: row=q=(r&3)+8*(r>>2)+4*h32, col=dk=dh*32+c32

  // staging (512 threads, 4 x uint4 each): K 128x64, V^T 64x128
  const int ksr = t >> 2;             // 0..127
  const int ksc = (t & 3) * 8;        // 0..24
  const u16* kgp = kb + (size_t)ksr * DK + ksc;
  u16* Kl = Ks + ksr * KSTR + ksc;
  const int vsr = t >> 3;             // 0..63
  const int vsc = (t & 7) * 8;        // 0..56
  const u16* vgp = vb + (size_t)vsr * S_LEN + vsc;
  u16* Vl = Vts + vsr * VSTR + vsc;

  uint4 kr0 = *(const uint4*)kgp;
  uint4 kr1 = *(const uint4*)(kgp + 32);
  uint4 vr0 = *(const uint4*)vgp;
  uint4 vr1 = *(const uint4*)(vgp + 64);
  float br = (t < 256) ? btp[t] : 0.f;

  const int krA = (kq * 32 + c32) * KSTR + h32 * 8;           // this wave's K-frag base
  const int bndcA = 127 + kq * 32 + 4 * h32 - grp * 32 - c32; // band base (>= 64 always)

  for (int kt = 0; kt < S_LEN; kt += 128) {
    *(uint4*)Kl = kr0;        *(uint4*)(Kl + 32) = kr1;
    *(uint4*)Vl = vr0;        *(uint4*)(Vl + 64) = vr1;
    if (t < 256) band[t] = br;
    __syncthreads();
    if (kt + 128 < S_LEN) {
      kr0 = *(const uint4*)(kgp + (size_t)(kt + 128) * DK);
      kr1 = *(const uint4*)(kgp + (size_t)(kt + 128) * DK + 32);
      vr0 = *(const uint4*)(vgp + (kt + 128));
      vr1 = *(const uint4*)(vgp + (kt + 128) + 64);
      br = (t < 256) ? btp[kt + 128 + t] : 0.f;
    }
    const int D = kt - q0;
    // far <=> all |delta| >= 128: min delta = D - 63, max = D + 127
    const bool far = (D >= 192) || (D <= -256);

    // QK^T (swapped): s = mfma(K, Q); this wave's 32-key quarter
    f32x16_t s4 = {};
    __builtin_amdgcn_s_setprio(1);
    #pragma unroll
    for (int kb4 = 0; kb4 < 4; ++kb4) {
      bf16x8_t kf = *(const bf16x8_t*)(Ks + krA + kb4 * 16);
      s4 = __builtin_amdgcn_mfma_f32_32x32x16_bf16(kf, qfrag[kb4], s4, 0, 0, 0);
    }
    __builtin_amdgcn_s_setprio(0);

    // softmax numerator: p[r] = exp2(s*log2e + band); key = kq*32+(r&3)+8*(r>>2)+4*h32, q=c32
    float p[16];
    if (far) {
      const float bfc = band[127];
      #pragma unroll
      for (int r = 0; r < 16; ++r)
        p[r] = fexp2(fmaf(s4[r], LOG2E, bfc));
    } else {
      #pragma unroll
      for (int r = 0; r < 16; ++r)
        p[r] = fexp2(fmaf(s4[r], LOG2E, band[bndcA + (r & 3) + 8 * (r >> 2)]));
    }
    #pragma unroll
    for (int r = 0; r < 16; ++r)
      lp += p[r];

    // pack P into PV A-fragments in-register (T12)
    union PW { u32 wds[4]; bf16x8_t v; } pa0, pa1;
    {
      u32 x, y;
      x = cvtpk(p[0], p[1]);   y = cvtpk(p[4], p[5]);   plswap(x, y);
      pa0.wds[0] = x; pa0.wds[2] = y;
      x = cvtpk(p[2], p[3]);   y = cvtpk(p[6], p[7]);   plswap(x, y);
      pa0.wds[1] = x; pa0.wds[3] = y;
      x = cvtpk(p[8], p[9]);   y = cvtpk(p[12], p[13]); plswap(x, y);
      pa1.wds[0] = x; pa1.wds[2] = y;
      x = cvtpk(p[10], p[11]); y = cvtpk(p[14], p[15]); plswap(x, y);
      pa1.wds[1] = x; pa1.wds[3] = y;
    }

    // PV: O[dh] += P[q][key16] * V[key16][dk]
    __builtin_amdgcn_s_setprio(1);
    {
      bf16x8_t vf00 = *(const bf16x8_t*)(Vts + (c32)      * VSTR + kq * 32 + h32 * 8);
      bf16x8_t vf01 = *(const bf16x8_t*)(Vts + (32 + c32) * VSTR + kq * 32 + h32 * 8);
      O0 = __builtin_amdgcn_mfma_f32_32x32x16_bf16(pa0.v, vf00, O0, 0, 0, 0);
      O1 = __builtin_amdgcn_mfma_f32_32x32x16_bf16(pa0.v, vf01, O1, 0, 0, 0);
      bf16x8_t vf10 = *(const bf16x8_t*)(Vts + (c32)      * VSTR + kq * 32 + 16 + h32 * 8);
      bf16x8_t vf11 = *(const bf16x8_t*)(Vts + (32 + c32) * VSTR + kq * 32 + 16 + h32 * 8);
      O0 = __builtin_amdgcn_mfma_f32_32x32x16_bf16(pa1.v, vf10, O0, 0, 0, 0);
      O1 = __builtin_amdgcn_mfma_f32_32x32x16_bf16(pa1.v, vf11, O1, 0, 0, 0);
    }
    __builtin_amdgcn_s_setprio(0);
    __syncthreads();   // all reads of Ks/Vts/band done before next iter's writes
  }

  // ---- epilogue: 2-round tree over 4 key-quarters; Ored aliases dead Ks/Vts (33792 <= 35840 B) ----
  lp += __shfl_xor(lp, 32, 64);          // both 32-lane halves now hold row-sum for q=c32 (this quarter)
  float (*Ored)[2][64][33] = (float (*)[2][64][33])smem;   // [grp][slot][lane][32]

  if (kq == 1 || kq == 3) {
    const int slot = kq >> 1;
    #pragma unroll
    for (int r = 0; r < 16; ++r) {
      Ored[grp][slot][l][r]      = O0[r];
      Ored[grp][slot][l][16 + r] = O1[r];
    }
  }
  if (kq != 0 && l < 32) lpx[(grp * 4 + kq) * 32 + l] = lp;
  __syncthreads();

  if (kq == 0) {
    #pragma unroll
    for (int r = 0; r < 16; ++r) {
      O0[r] += Ored[grp][0][l][r];
      O1[r] += Ored[grp][0][l][16 + r];
    }
  } else if (kq == 2) {
    #pragma unroll
    for (int r = 0; r < 16; ++r) {
      O0[r] += Ored[grp][1][l][r];
      O1[r] += Ored[grp][1][l][16 + r];
    }
    #pragma unroll
    for (int r = 0; r < 16; ++r) {
      Ored[grp][1][l][r]      = O0[r];
      Ored[grp][1][l][16 + r] = O1[r];
    }
  }
  __syncthreads();

  if (kq == 0) {
    #pragma unroll
    for (int r = 0; r < 16; ++r) {
      O0[r] += Ored[grp][1][l][r];
      O1[r] += Ored[grp][1][l][16 + r];
    }
    lp += lpx[(grp * 4 + 1) * 32 + c32] + lpx[(grp * 4 + 2) * 32 + c32] + lpx[(grp * 4 + 3) * 32 + c32];
    float rv = 1.0f / lp;            // valid in every lane for q = c32
    #pragma unroll
    for (int r = 0; r < 16; ++r) {
      int qr = (r & 3) + 8 * (r >> 2) + 4 * h32;     // q within group
      float inv = __shfl(rv, qr, 64);
      int s = q0 + grp * 32 + qr;
      u16* cp = ctx + ((size_t)(b * S_LEN + s)) * DMODEL + h * DK;
      cp[c32]      = f2b(O0[r] * inv);
      cp[32 + c32] = f2b(O1[r] * inv);
    }
  }
}

extern "C" void kernel_launch(void* const* d_in, const int* in_sizes, int n_in,
                              void* d_out, int out_size, void* d_ws, size_t ws_size,
                              hipStream_t stream) {
  const float* x   = (const float*)d_in[0];
  const float* Wq  = (const float*)d_in[1];
  const float* Wk  = (const float*)d_in[2];
  const float* Wv  = (const float*)d_in[3];
  const float* Wo  = (const float*)d_in[4];
  const float* rel = (const float*)d_in[5];
  float* out = (float*)d_out;

  char* ws = (char*)d_ws;
  size_t off = 0;
  auto carve = [&](size_t bytes) -> char* {
    char* p = ws + off;
    off += (bytes + 255) & ~(size_t)255;
    return p;
  };
  u16*   xb   = (u16*)  carve((size_t)MROWS * DMODEL * 2);       // x bf16
  u16*   Wall = (u16*)  carve((size_t)3 * DMODEL * DMODEL * 2);  // [Wq^T;Wk^T;Wv^T] bf16 [3072][1024]
  u16*   Wto  = (u16*)  carve((size_t)DMODEL * DMODEL * 2);
  u16*   qb16 = (u16*)  carve((size_t)4194304 * 2);              // [bh][s][64] bf16
  u16*   kb16 = (u16*)  carve((size_t)4194304 * 2);
  u16*   vt16 = (u16*)  carve((size_t)4194304 * 2);              // [bh][64][s] bf16
  float* btab = (float*)carve(((size_t)NH * 4095 + 256) * 4);    // +tail slack (band stage)
  u16*   ctxb = (u16*)  carve((size_t)4194304 * 2);              // [b][s][1024] bf16

  prep_kernel<<<8448, 256, 0, stream>>>(x, Wq, Wk, Wv, Wo, rel, xb, Wall, Wto, btab);

  dim3 qkvgrid(32, 24);  // M/128, 3072/128
  gemm128_kernel<1><<<qkvgrid, 256, 0, stream>>>(xb, Wall, nullptr, qb16, kb16, vt16);

  attn_mfma_kernel<<<1024, 512, 0, stream>>>(qb16, kb16, vt16, btab, ctxb);

  dim3 ogrid(32, 8);
  gemm128_kernel<0><<<ogrid, 256, 0, stream>>>(ctxb, Wto, out, nullptr, nullptr, nullptr);
}

// Round 7
// 193.267 us; speedup vs baseline: 2.7790x; 2.7790x over previous
//
#include <hip/hip_runtime.h>
#include <math.h>

typedef unsigned short u16;
typedef unsigned int u32;
typedef __attribute__((ext_vector_type(8))) short bf16x8_t;
typedef __attribute__((ext_vector_type(4))) float f32x4_t;
typedef __attribute__((ext_vector_type(16))) float f32x16_t;

#define S_LEN  2048
#define NH     16
#define DK     64
#define DMODEL 1024
#define MROWS  4096   // B*S
#define LOG2E  1.44269504088896f

__device__ inline u16 f2b(float f) {
  union { float f; u32 u; } c; c.f = f;
  u32 u = c.u;
  return (u16)((u + 0x7fffu + ((u >> 16) & 1u)) >> 16);  // RNE bf16
}

__device__ __forceinline__ float fexp2(float x) {
#if __has_builtin(__builtin_amdgcn_exp2f)
  return __builtin_amdgcn_exp2f(x);
#else
  return exp2f(x);
#endif
}

__device__ __forceinline__ u32 cvtpk(float lo, float hi) {
  u32 r;
  asm("v_cvt_pk_bf16_f32 %0, %1, %2" : "=v"(r) : "v"(lo), "v"(hi));
  return r;
}

// swap x's high-32-lane half with y's low-32-lane half (gfx950 v_permlane32_swap_b32)
__device__ __forceinline__ void plswap(u32 &x, u32 &y) {
  asm("v_permlane32_swap_b32 %0, %1" : "+v"(x), "+v"(y));
}

// ---------------- global -> LDS DMA: wave-uniform LDS base, lane deposits 16B at base + lane*16 ----------------
__device__ __forceinline__ void stage16(const u16* gp_lane, u16* lds_base) {
#if __has_builtin(__builtin_amdgcn_global_load_lds)
  __builtin_amdgcn_global_load_lds((const __attribute__((address_space(1))) u32*)gp_lane,
                                   (__attribute__((address_space(3))) u32*)lds_base, 16, 0, 0);
#else
  *(uint4*)(lds_base + (threadIdx.x & 63) * 8) = *(const uint4*)gp_lane;
#endif
}

// ---------------- fused prep: cast x, transpose+cast 4 weights, bias table ----------------
__global__ void prep_kernel(const float* __restrict__ x,
                            const float* __restrict__ Wq, const float* __restrict__ Wk,
                            const float* __restrict__ Wv, const float* __restrict__ Wo,
                            const float* __restrict__ rel,
                            u16* __restrict__ xb, u16* __restrict__ Wall,
                            u16* __restrict__ Wto, float* __restrict__ btab) {
  __shared__ float tile[32][33];
  const int bid = blockIdx.x, t = threadIdx.x;
  if (bid < 4096) {
    int i = (bid * 256 + t) * 4;
    float4 v = *(const float4*)(x + i);
    ushort4 o;
    o.x = f2b(v.x); o.y = f2b(v.y); o.z = f2b(v.z); o.w = f2b(v.w);
    *(ushort4*)(xb + i) = o;
  } else if (bid < 8192) {
    int bid2 = bid - 4096;
    int z = bid2 >> 10, rem = bid2 & 1023;
    const float* W; u16* Wt;
    switch (z) {
      case 0: W = Wq; Wt = Wall; break;
      case 1: W = Wk; Wt = Wall + (size_t)DMODEL * DMODEL; break;
      case 2: W = Wv; Wt = Wall + (size_t)2 * DMODEL * DMODEL; break;
      default: W = Wo; Wt = Wto; break;
    }
    int bc = (rem & 31) * 32, br = (rem >> 5) * 32;
    int tx = t & 31, ty = t >> 5;
    #pragma unroll
    for (int yy = 0; yy < 32; yy += 8)
      tile[ty + yy][tx] = W[(size_t)(br + ty + yy) * DMODEL + bc + tx];
    __syncthreads();
    #pragma unroll
    for (int yy = 0; yy < 32; yy += 8)
      Wt[(size_t)(bc + ty + yy) * DMODEL + br + tx] = f2b(tile[tx][ty + yy]);
  } else {
    // bias table: btab[h][delta+2047] = (bias(h,delta) - 16) * log2(e)   [exp2-domain]
    int idx = (bid - 8192) * 256 + t;
    if (idx < NH * 4095) {
      int h = idx / 4095;
      int dpos = idx - h * 4095;
      int delta = dpos - 2047;               // j - i; reference n = i - j
      int ret = (delta > 0) ? 16 : 0;
      int n = delta < 0 ? -delta : delta;
      int bucket;
      if (n < 8) {
        bucket = ret + n;
      } else {
        float vf = logf((float)n * 0.125f) / 2.7725887222397811f * 8.0f;
        int vil = 8 + (int)vf;
        bucket = ret + (vil < 15 ? vil : 15);
      }
      btab[idx] = (rel[bucket * NH + h] - 16.0f) * LOG2E;
    }
  }
}

// ---------------- 128x128 bf16 MFMA GEMM ----------------
#define GSTR 56   // manual-path LDS row stride (112 B): 16B-aligned, 2-way bank aliasing (free)
template <int MODE>
__global__ __launch_bounds__(256) void gemm128_kernel(const u16* __restrict__ A,
                                                      const u16* __restrict__ Bt,
                                                      float* __restrict__ C,
                                                      u16* __restrict__ q16,
                                                      u16* __restrict__ k16,
                                                      u16* __restrict__ vt16) {
  constexpr int ABSZ = (MODE == 1) ? 4608 : 128 * GSTR;
  constexpr int FSTR = (MODE == 1) ? 32 : GSTR;
  __shared__ __align__(16) u16 As[ABSZ];
  __shared__ __align__(16) u16 Bs[ABSZ];
  const int t = threadIdx.x, w = t >> 6, l = t & 63;
  const int c = l & 15, quad = l >> 4;
  const int m0 = blockIdx.x * 128, n0 = blockIdx.y * 128;
  const int wm = (w & 1) * 64, wn = (w >> 1) * 64;

  f32x4_t acc[16] = {};

  if constexpr (MODE == 1) {
    const int sr = l >> 2;
    const int k8 = (l & 3) * 8;
    const u16* Ag0 = A  + (size_t)(m0 + w * 32 + sr) * DMODEL + k8;
    const u16* Ag1 = Ag0 + (size_t)16 * DMODEL;
    const u16* Bg0 = Bt + (size_t)(n0 + w * 32 + sr) * DMODEL + k8;
    const u16* Bg1 = Bg0 + (size_t)16 * DMODEL;
    u16* Al = As + w * 1024;
    u16* Bl = Bs + w * 1024;
    for (int k0 = 0; k0 < DMODEL; k0 += 32) {
      __syncthreads();
      stage16(Ag0 + k0, Al);
      stage16(Ag1 + k0, Al + 512);
      stage16(Bg0 + k0, Bl);
      stage16(Bg1 + k0, Bl + 512);
      __syncthreads();
      bf16x8_t af[4], bfr[4];
      #pragma unroll
      for (int i = 0; i < 4; ++i) {
        af[i]  = *(const bf16x8_t*)(As + (wm + i * 16 + c) * FSTR + quad * 8);
        bfr[i] = *(const bf16x8_t*)(Bs + (wn + i * 16 + c) * FSTR + quad * 8);
      }
      #pragma unroll
      for (int mt = 0; mt < 4; ++mt)
        #pragma unroll
        for (int nt = 0; nt < 4; ++nt)
          acc[mt * 4 + nt] = __builtin_amdgcn_mfma_f32_16x16x32_bf16(af[mt], bfr[nt], acc[mt * 4 + nt], 0, 0, 0);
    }
  } else {
    const int sr = t >> 2;
    const int k8 = (t & 3) * 8;
    const u16* Ag0 = A  + (size_t)(m0 + sr) * DMODEL + k8;
    const u16* Ag1 = Ag0 + (size_t)64 * DMODEL;
    const u16* Bg0 = Bt + (size_t)(n0 + sr) * DMODEL + k8;
    const u16* Bg1 = Bg0 + (size_t)64 * DMODEL;
    u16* Al0 = As + sr * GSTR + k8;
    u16* Al1 = Al0 + 64 * GSTR;
    u16* Bl0 = Bs + sr * GSTR + k8;
    u16* Bl1 = Bl0 + 64 * GSTR;

    uint4 a0 = *(const uint4*)Ag0, a1 = *(const uint4*)Ag1;
    uint4 b0 = *(const uint4*)Bg0, b1 = *(const uint4*)Bg1;
    for (int k0 = 0; k0 < DMODEL; k0 += 32) {
      __syncthreads();
      *(uint4*)Al0 = a0; *(uint4*)Al1 = a1;
      *(uint4*)Bl0 = b0; *(uint4*)Bl1 = b1;
      __syncthreads();
      if (k0 + 32 < DMODEL) {
        a0 = *(const uint4*)(Ag0 + k0 + 32);
        a1 = *(const uint4*)(Ag1 + k0 + 32);
        b0 = *(const uint4*)(Bg0 + k0 + 32);
        b1 = *(const uint4*)(Bg1 + k0 + 32);
      }
      bf16x8_t af[4], bfr[4];
      #pragma unroll
      for (int i = 0; i < 4; ++i) {
        af[i]  = *(const bf16x8_t*)(As + (wm + i * 16 + c) * FSTR + quad * 8);
        bfr[i] = *(const bf16x8_t*)(Bs + (wn + i * 16 + c) * FSTR + quad * 8);
      }
      #pragma unroll
      for (int mt = 0; mt < 4; ++mt)
        #pragma unroll
        for (int nt = 0; nt < 4; ++nt)
          acc[mt * 4 + nt] = __builtin_amdgcn_mfma_f32_16x16x32_bf16(af[mt], bfr[nt], acc[mt * 4 + nt], 0, 0, 0);
    }
  }

  if constexpr (MODE == 0) {
    #pragma unroll
    for (int mt = 0; mt < 4; ++mt) {
      int grow0 = m0 + wm + mt * 16 + quad * 4;
      #pragma unroll
      for (int nt = 0; nt < 4; ++nt) {
        int gcol = n0 + wn + nt * 16 + c;
        #pragma unroll
        for (int r = 0; r < 4; ++r)
          C[(size_t)(grow0 + r) * DMODEL + gcol] = acc[mt * 4 + nt][r];
      }
    }
  } else {
    const int whichblk = n0 >> 10;
    if (whichblk == 2) {
      #pragma unroll
      for (int mt = 0; mt < 4; ++mt) {
        int grow0 = m0 + wm + mt * 16 + quad * 4;
        int b = grow0 >> 11, s0 = grow0 & 2047;
        #pragma unroll
        for (int nt = 0; nt < 4; ++nt) {
          int cc = (n0 + wn + nt * 16 + c) & 1023;
          int hh = cc >> 6, dk = cc & 63;
          f32x4_t v4 = acc[mt * 4 + nt];
          ushort4 o;
          o.x = f2b(v4[0]); o.y = f2b(v4[1]); o.z = f2b(v4[2]); o.w = f2b(v4[3]);
          *(ushort4*)(vt16 + (((size_t)(b * NH + hh)) * DK + dk) * S_LEN + s0) = o;
        }
      }
    } else {
      u16* tb = (w & 1) ? Bs : As;
      const int base_mw = m0 + wm;
      const int bb = base_mw >> 11, s0g = base_mw & 2047;
      const int cc = (n0 + wn) & 1023;
      const int hh = cc >> 6;
      u16* qk = (whichblk == 0 ? q16 : k16) + (((size_t)(bb * NH + hh)) * S_LEN + s0g) * DK;
      __syncthreads();
      #pragma unroll
      for (int round = 0; round < 2; ++round) {
        if ((w >> 1) == round) {
          #pragma unroll
          for (int mt = 0; mt < 4; ++mt)
            #pragma unroll
            for (int nt = 0; nt < 4; ++nt)
              #pragma unroll
              for (int r = 0; r < 4; ++r)
                tb[(mt * 16 + quad * 4 + r) * 72 + nt * 16 + c] = f2b(acc[mt * 4 + nt][r]);
          #pragma unroll
          for (int i = 0; i < 8; ++i) {
            int lrow = i * 8 + (l >> 3);
            int chk = l & 7;
            uint4 vv = *(const uint4*)(tb + lrow * 72 + chk * 8);
            *(uint4*)(qk + (size_t)lrow * DK + chk * 8) = vv;
          }
        }
        __syncthreads();
      }
    }
  }
}

// ---------------- MFMA flash attention v7: v6 structure, launch_bounds relaxed to (512,4) ----------------
// R6 post-mortem: (512,8) forced a 64-VGPR budget -> compiler allocated 32 VGPR and SPILLED the
// f32x16 O-accumulators to scratch (FETCH 756 MB, 414 us). The occupancy mechanism itself worked
// (OccupancyPercent 77). Fix: (512,4) — the bound under which this exact inner loop compiled to
// 64 VGPR spill-free in R5. Residency stays LDS-limited at 4 blocks/CU (37.9 KB x 4 = 151.6 KB),
// so the 1024-block grid still yields the 32-wave/CU cap.
// 8 waves = 2 q-groups (32 q) x 4 key-quarters (32 keys of a 128-key tile).
#define KSTR 72    // K row stride in u16 (144 B): conflict-free frag reads (R3-proven)
#define VSTR 136   // V^T row stride in u16 (272 B): same 16B-shift-per-row class
__global__ __launch_bounds__(512, 4) void attn_mfma_kernel(const u16* __restrict__ q,
                                                           const u16* __restrict__ k,
                                                           const u16* __restrict__ vt,
                                                           const float* __restrict__ btab,
                                                           u16* __restrict__ ctx) {
  __shared__ __align__(16) char smem[37888];
  u16*   Ks   = (u16*)smem;                   // [128][KSTR]  18432 B
  u16*   Vts  = (u16*)(smem + 18432);         // [64][VSTR]   17408 B
  float* band = (float*)(smem + 35840);       // [256]         1024 B
  float* lpx  = (float*)(smem + 36864);       // [2][4][32]    1024 B

  const int t = threadIdx.x;
  const int w = t >> 6, l = t & 63;
  const int c32 = l & 31, h32 = l >> 5;
  const int grp = w >> 2, kq = w & 3;

  // bijective XCD swizzle (1024 % 8 == 0): each XCD gets 128 consecutive swz = 4 bh
  const int orig = blockIdx.x;                 // 0..1023
  const int swz = (orig & 7) * 128 + (orig >> 3);
  const int bh = swz >> 5;                     // 0..31
  const int q0 = (swz & 31) * 64;
  const int h = bh & (NH - 1), b = bh >> 4;

  const u16* qb = q + (size_t)bh * S_LEN * DK;
  const u16* kb = k + (size_t)bh * S_LEN * DK;
  const u16* vb = vt + (size_t)bh * DK * S_LEN;
  const float* btp = btab + h * 4095 + (2047 - 127 - q0);

  // Q fragments (B operand of 32x32x16): lane holds Q[q = c32][dk = kb4*16 + h32*8 + j]
  bf16x8_t qfrag[4];
  {
    const u16* qp = qb + (size_t)(q0 + grp * 32 + c32) * DK + h32 * 8;
    qfrag[0] = *(const bf16x8_t*)(qp);
    qfrag[1] = *(const bf16x8_t*)(qp + 16);
    qfrag[2] = *(const bf16x8_t*)(qp + 32);
    qfrag[3] = *(const bf16x8_t*)(qp + 48);
  }

  float lp = 0.f;
  f32x16_t O0 = {}, O1 = {};   // O: row=q=(r&3)+8*(r>>2)+4*h32, col=dk=dh*32+c32

  // staging (512 threads, 4 x uint4 each): K 128x64, V^T 64x128
  const int ksr = t >> 2;             // 0..127
  const int ksc = (t & 3) * 8;        // 0..24
  const u16* kgp = kb + (size_t)ksr * DK + ksc;
  u16* Kl = Ks + ksr * KSTR + ksc;
  const int vsr = t >> 3;             // 0..63
  const int vsc = (t & 7) * 8;        // 0..56
  const u16* vgp = vb + (size_t)vsr * S_LEN + vsc;
  u16* Vl = Vts + vsr * VSTR + vsc;

  uint4 kr0 = *(const uint4*)kgp;
  uint4 kr1 = *(const uint4*)(kgp + 32);
  uint4 vr0 = *(const uint4*)vgp;
  uint4 vr1 = *(const uint4*)(vgp + 64);
  float br = (t < 256) ? btp[t] : 0.f;

  const int krA = (kq * 32 + c32) * KSTR + h32 * 8;           // this wave's K-frag base
  const int bndcA = 127 + kq * 32 + 4 * h32 - grp * 32 - c32; // band base (>= 64 always)

  for (int kt = 0; kt < S_LEN; kt += 128) {
    *(uint4*)Kl = kr0;        *(uint4*)(Kl + 32) = kr1;
    *(uint4*)Vl = vr0;        *(uint4*)(Vl + 64) = vr1;
    if (t < 256) band[t] = br;
    __syncthreads();
    if (kt + 128 < S_LEN) {
      kr0 = *(const uint4*)(kgp + (size_t)(kt + 128) * DK);
      kr1 = *(const uint4*)(kgp + (size_t)(kt + 128) * DK + 32);
      vr0 = *(const uint4*)(vgp + (kt + 128));
      vr1 = *(const uint4*)(vgp + (kt + 128) + 64);
      br = (t < 256) ? btp[kt + 128 + t] : 0.f;
    }
    const int D = kt - q0;
    // far <=> all |delta| >= 128: min delta = D - 63, max = D + 127
    const bool far = (D >= 192) || (D <= -256);

    // QK^T (swapped): s = mfma(K, Q); this wave's 32-key quarter
    f32x16_t s4 = {};
    __builtin_amdgcn_s_setprio(1);
    #pragma unroll
    for (int kb4 = 0; kb4 < 4; ++kb4) {
      bf16x8_t kf = *(const bf16x8_t*)(Ks + krA + kb4 * 16);
      s4 = __builtin_amdgcn_mfma_f32_32x32x16_bf16(kf, qfrag[kb4], s4, 0, 0, 0);
    }
    __builtin_amdgcn_s_setprio(0);

    // softmax numerator: p[r] = exp2(s*log2e + band); key = kq*32+(r&3)+8*(r>>2)+4*h32, q=c32
    float p[16];
    if (far) {
      const float bfc = band[127];
      #pragma unroll
      for (int r = 0; r < 16; ++r)
        p[r] = fexp2(fmaf(s4[r], LOG2E, bfc));
    } else {
      #pragma unroll
      for (int r = 0; r < 16; ++r)
        p[r] = fexp2(fmaf(s4[r], LOG2E, band[bndcA + (r & 3) + 8 * (r >> 2)]));
    }
    #pragma unroll
    for (int r = 0; r < 16; ++r)
      lp += p[r];

    // pack P into PV A-fragments in-register (T12)
    union PW { u32 wds[4]; bf16x8_t v; } pa0, pa1;
    {
      u32 x, y;
      x = cvtpk(p[0], p[1]);   y = cvtpk(p[4], p[5]);   plswap(x, y);
      pa0.wds[0] = x; pa0.wds[2] = y;
      x = cvtpk(p[2], p[3]);   y = cvtpk(p[6], p[7]);   plswap(x, y);
      pa0.wds[1] = x; pa0.wds[3] = y;
      x = cvtpk(p[8], p[9]);   y = cvtpk(p[12], p[13]); plswap(x, y);
      pa1.wds[0] = x; pa1.wds[2] = y;
      x = cvtpk(p[10], p[11]); y = cvtpk(p[14], p[15]); plswap(x, y);
      pa1.wds[1] = x; pa1.wds[3] = y;
    }

    // PV: O[dh] += P[q][key16] * V[key16][dk]
    __builtin_amdgcn_s_setprio(1);
    {
      bf16x8_t vf00 = *(const bf16x8_t*)(Vts + (c32)      * VSTR + kq * 32 + h32 * 8);
      bf16x8_t vf01 = *(const bf16x8_t*)(Vts + (32 + c32) * VSTR + kq * 32 + h32 * 8);
      O0 = __builtin_amdgcn_mfma_f32_32x32x16_bf16(pa0.v, vf00, O0, 0, 0, 0);
      O1 = __builtin_amdgcn_mfma_f32_32x32x16_bf16(pa0.v, vf01, O1, 0, 0, 0);
      bf16x8_t vf10 = *(const bf16x8_t*)(Vts + (c32)      * VSTR + kq * 32 + 16 + h32 * 8);
      bf16x8_t vf11 = *(const bf16x8_t*)(Vts + (32 + c32) * VSTR + kq * 32 + 16 + h32 * 8);
      O0 = __builtin_amdgcn_mfma_f32_32x32x16_bf16(pa1.v, vf10, O0, 0, 0, 0);
      O1 = __builtin_amdgcn_mfma_f32_32x32x16_bf16(pa1.v, vf11, O1, 0, 0, 0);
    }
    __builtin_amdgcn_s_setprio(0);
    __syncthreads();   // all reads of Ks/Vts/band done before next iter's writes
  }

  // ---- epilogue: 2-round tree over 4 key-quarters; Ored aliases dead Ks/Vts (33792 <= 35840 B) ----
  lp += __shfl_xor(lp, 32, 64);          // both 32-lane halves now hold row-sum for q=c32 (this quarter)
  float (*Ored)[2][64][33] = (float (*)[2][64][33])smem;   // [grp][slot][lane][32]

  if (kq == 1 || kq == 3) {
    const int slot = kq >> 1;
    #pragma unroll
    for (int r = 0; r < 16; ++r) {
      Ored[grp][slot][l][r]      = O0[r];
      Ored[grp][slot][l][16 + r] = O1[r];
    }
  }
  if (kq != 0 && l < 32) lpx[(grp * 4 + kq) * 32 + l] = lp;
  __syncthreads();

  if (kq == 0) {
    #pragma unroll
    for (int r = 0; r < 16; ++r) {
      O0[r] += Ored[grp][0][l][r];
      O1[r] += Ored[grp][0][l][16 + r];
    }
  } else if (kq == 2) {
    #pragma unroll
    for (int r = 0; r < 16; ++r) {
      O0[r] += Ored[grp][1][l][r];
      O1[r] += Ored[grp][1][l][16 + r];
    }
    #pragma unroll
    for (int r = 0; r < 16; ++r) {
      Ored[grp][1][l][r]      = O0[r];
      Ored[grp][1][l][16 + r] = O1[r];
    }
  }
  __syncthreads();

  if (kq == 0) {
    #pragma unroll
    for (int r = 0; r < 16; ++r) {
      O0[r] += Ored[grp][1][l][r];
      O1[r] += Ored[grp][1][l][16 + r];
    }
    lp += lpx[(grp * 4 + 1) * 32 + c32] + lpx[(grp * 4 + 2) * 32 + c32] + lpx[(grp * 4 + 3) * 32 + c32];
    float rv = 1.0f / lp;            // valid in every lane for q = c32
    #pragma unroll
    for (int r = 0; r < 16; ++r) {
      int qr = (r & 3) + 8 * (r >> 2) + 4 * h32;     // q within group
      float inv = __shfl(rv, qr, 64);
      int s = q0 + grp * 32 + qr;
      u16* cp = ctx + ((size_t)(b * S_LEN + s)) * DMODEL + h * DK;
      cp[c32]      = f2b(O0[r] * inv);
      cp[32 + c32] = f2b(O1[r] * inv);
    }
  }
}

extern "C" void kernel_launch(void* const* d_in, const int* in_sizes, int n_in,
                              void* d_out, int out_size, void* d_ws, size_t ws_size,
                              hipStream_t stream) {
  const float* x   = (const float*)d_in[0];
  const float* Wq  = (const float*)d_in[1];
  const float* Wk  = (const float*)d_in[2];
  const float* Wv  = (const float*)d_in[3];
  const float* Wo  = (const float*)d_in[4];
  const float* rel = (const float*)d_in[5];
  float* out = (float*)d_out;

  char* ws = (char*)d_ws;
  size_t off = 0;
  auto carve = [&](size_t bytes) -> char* {
    char* p = ws + off;
    off += (bytes + 255) & ~(size_t)255;
    return p;
  };
  u16*   xb   = (u16*)  carve((size_t)MROWS * DMODEL * 2);       // x bf16
  u16*   Wall = (u16*)  carve((size_t)3 * DMODEL * DMODEL * 2);  // [Wq^T;Wk^T;Wv^T] bf16 [3072][1024]
  u16*   Wto  = (u16*)  carve((size_t)DMODEL * DMODEL * 2);
  u16*   qb16 = (u16*)  carve((size_t)4194304 * 2);              // [bh][s][64] bf16
  u16*   kb16 = (u16*)  carve((size_t)4194304 * 2);
  u16*   vt16 = (u16*)  carve((size_t)4194304 * 2);              // [bh][64][s] bf16
  float* btab = (float*)carve(((size_t)NH * 4095 + 256) * 4);    // +tail slack (band stage)
  u16*   ctxb = (u16*)  carve((size_t)4194304 * 2);              // [b][s][1024] bf16

  prep_kernel<<<8448, 256, 0, stream>>>(x, Wq, Wk, Wv, Wo, rel, xb, Wall, Wto, btab);

  dim3 qkvgrid(32, 24);  // M/128, 3072/128
  gemm128_kernel<1><<<qkvgrid, 256, 0, stream>>>(xb, Wall, nullptr, qb16, kb16, vt16);

  attn_mfma_kernel<<<1024, 512, 0, stream>>>(qb16, kb16, vt16, btab, ctxb);

  dim3 ogrid(32, 8);
  gemm128_kernel<0><<<ogrid, 256, 0, stream>>>(ctxb, Wto, out, nullptr, nullptr, nullptr);
}

// Round 8
// 180.200 us; speedup vs baseline: 2.9805x; 1.0725x over previous
//
#include <hip/hip_runtime.h>
#include <math.h>

typedef unsigned short u16;
typedef unsigned int u32;
typedef __attribute__((ext_vector_type(8))) short bf16x8_t;
typedef __attribute__((ext_vector_type(4))) float f32x4_t;
typedef __attribute__((ext_vector_type(16))) float f32x16_t;

#define S_LEN  2048
#define NH     16
#define DK     64
#define DMODEL 1024
#define MROWS  4096   // B*S
#define LOG2E  1.44269504088896f

__device__ inline u16 f2b(float f) {
  union { float f; u32 u; } c; c.f = f;
  u32 u = c.u;
  return (u16)((u + 0x7fffu + ((u >> 16) & 1u)) >> 16);  // RNE bf16
}

__device__ __forceinline__ float fexp2(float x) {
#if __has_builtin(__builtin_amdgcn_exp2f)
  return __builtin_amdgcn_exp2f(x);
#else
  return exp2f(x);
#endif
}

__device__ __forceinline__ u32 cvtpk(float lo, float hi) {
  u32 r;
  asm("v_cvt_pk_bf16_f32 %0, %1, %2" : "=v"(r) : "v"(lo), "v"(hi));
  return r;
}

// swap x's high-32-lane half with y's low-32-lane half (gfx950 v_permlane32_swap_b32)
__device__ __forceinline__ void plswap(u32 &x, u32 &y) {
  asm("v_permlane32_swap_b32 %0, %1" : "+v"(x), "+v"(y));
}

// ---------------- global -> LDS DMA: wave-uniform LDS base, lane deposits 16B at base + lane*16 ----------------
__device__ __forceinline__ void stage16(const u16* gp_lane, u16* lds_base) {
#if __has_builtin(__builtin_amdgcn_global_load_lds)
  __builtin_amdgcn_global_load_lds((const __attribute__((address_space(1))) u32*)gp_lane,
                                   (__attribute__((address_space(3))) u32*)lds_base, 16, 0, 0);
#else
  *(uint4*)(lds_base + (threadIdx.x & 63) * 8) = *(const uint4*)gp_lane;
#endif
}

// ---------------- fused prep: cast x, transpose+cast 4 weights, bias table ----------------
__global__ void prep_kernel(const float* __restrict__ x,
                            const float* __restrict__ Wq, const float* __restrict__ Wk,
                            const float* __restrict__ Wv, const float* __restrict__ Wo,
                            const float* __restrict__ rel,
                            u16* __restrict__ xb, u16* __restrict__ Wall,
                            u16* __restrict__ Wto, float* __restrict__ btab) {
  __shared__ float tile[32][33];
  const int bid = blockIdx.x, t = threadIdx.x;
  if (bid < 4096) {
    int i = (bid * 256 + t) * 4;
    float4 v = *(const float4*)(x + i);
    ushort4 o;
    o.x = f2b(v.x); o.y = f2b(v.y); o.z = f2b(v.z); o.w = f2b(v.w);
    *(ushort4*)(xb + i) = o;
  } else if (bid < 8192) {
    int bid2 = bid - 4096;
    int z = bid2 >> 10, rem = bid2 & 1023;
    const float* W; u16* Wt;
    switch (z) {
      case 0: W = Wq; Wt = Wall; break;
      case 1: W = Wk; Wt = Wall + (size_t)DMODEL * DMODEL; break;
      case 2: W = Wv; Wt = Wall + (size_t)2 * DMODEL * DMODEL; break;
      default: W = Wo; Wt = Wto; break;
    }
    int bc = (rem & 31) * 32, br = (rem >> 5) * 32;
    int tx = t & 31, ty = t >> 5;
    #pragma unroll
    for (int yy = 0; yy < 32; yy += 8)
      tile[ty + yy][tx] = W[(size_t)(br + ty + yy) * DMODEL + bc + tx];
    __syncthreads();
    #pragma unroll
    for (int yy = 0; yy < 32; yy += 8)
      Wt[(size_t)(bc + ty + yy) * DMODEL + br + tx] = f2b(tile[tx][ty + yy]);
  } else {
    // bias table: btab[h][delta+2047] = (bias(h,delta) - 16) * log2(e)   [exp2-domain]
    int idx = (bid - 8192) * 256 + t;
    if (idx < NH * 4095) {
      int h = idx / 4095;
      int dpos = idx - h * 4095;
      int delta = dpos - 2047;               // j - i; reference n = i - j
      int ret = (delta > 0) ? 16 : 0;
      int n = delta < 0 ? -delta : delta;
      int bucket;
      if (n < 8) {
        bucket = ret + n;
      } else {
        float vf = logf((float)n * 0.125f) / 2.7725887222397811f * 8.0f;
        int vil = 8 + (int)vf;
        bucket = ret + (vil < 15 ? vil : 15);
      }
      btab[idx] = (rel[bucket * NH + h] - 16.0f) * LOG2E;
    }
  }
}

// ---------------- bf16 MFMA GEMM ----------------
// MODE 1: fused QKV, 128x128 tile, grid (32,24)=768 blocks=3/CU; m97-style global_load_lds DMA.
// MODE 0: out-projection, 128x64 tile, grid (32,16)=512 blocks=2/CU (was 128x128 @ 1/CU --
//         occupancy cap 12.5%; halving the N-tile doubles residency; A/B sets are L2/L3-resident
//         so the 1.5x staging-per-output is cheap). Manual staging + register prefetch (R5-proven).
#define GSTR 56   // manual-path LDS row stride (112 B): 16B-aligned, 2-way bank aliasing (free)
template <int MODE>
__global__ __launch_bounds__(256) void gemm128_kernel(const u16* __restrict__ A,
                                                      const u16* __restrict__ Bt,
                                                      float* __restrict__ C,
                                                      u16* __restrict__ q16,
                                                      u16* __restrict__ k16,
                                                      u16* __restrict__ vt16) {
  constexpr int ABSZ = (MODE == 1) ? 4608 : 128 * GSTR;
  constexpr int BSZ  = (MODE == 1) ? 4608 : 64 * GSTR;
  constexpr int FSTR = (MODE == 1) ? 32 : GSTR;
  __shared__ __align__(16) u16 As[ABSZ];
  __shared__ __align__(16) u16 Bs[BSZ];
  const int t = threadIdx.x, w = t >> 6, l = t & 63;
  const int c = l & 15, quad = l >> 4;
  const int m0 = blockIdx.x * 128;
  const int n0 = blockIdx.y * ((MODE == 1) ? 128 : 64);
  const int wm = (w & 1) * 64;
  const int wn = (w >> 1) * ((MODE == 1) ? 64 : 32);

  f32x4_t acc[16] = {};

  if constexpr (MODE == 1) {
    const int sr = l >> 2;
    const int k8 = (l & 3) * 8;
    const u16* Ag0 = A  + (size_t)(m0 + w * 32 + sr) * DMODEL + k8;
    const u16* Ag1 = Ag0 + (size_t)16 * DMODEL;
    const u16* Bg0 = Bt + (size_t)(n0 + w * 32 + sr) * DMODEL + k8;
    const u16* Bg1 = Bg0 + (size_t)16 * DMODEL;
    u16* Al = As + w * 1024;
    u16* Bl = Bs + w * 1024;
    for (int k0 = 0; k0 < DMODEL; k0 += 32) {
      __syncthreads();
      stage16(Ag0 + k0, Al);
      stage16(Ag1 + k0, Al + 512);
      stage16(Bg0 + k0, Bl);
      stage16(Bg1 + k0, Bl + 512);
      __syncthreads();
      bf16x8_t af[4], bfr[4];
      #pragma unroll
      for (int i = 0; i < 4; ++i) {
        af[i]  = *(const bf16x8_t*)(As + (wm + i * 16 + c) * FSTR + quad * 8);
        bfr[i] = *(const bf16x8_t*)(Bs + (wn + i * 16 + c) * FSTR + quad * 8);
      }
      #pragma unroll
      for (int mt = 0; mt < 4; ++mt)
        #pragma unroll
        for (int nt = 0; nt < 4; ++nt)
          acc[mt * 4 + nt] = __builtin_amdgcn_mfma_f32_16x16x32_bf16(af[mt], bfr[nt], acc[mt * 4 + nt], 0, 0, 0);
    }
  } else {
    // manual staging + register prefetch; A: 128x32, B: 64x32 per K-step
    const int sr = t >> 2;              // 0..63
    const int k8 = (t & 3) * 8;
    const u16* Ag0 = A  + (size_t)(m0 + sr) * DMODEL + k8;
    const u16* Ag1 = Ag0 + (size_t)64 * DMODEL;
    const u16* Bg0 = Bt + (size_t)(n0 + sr) * DMODEL + k8;
    u16* Al0 = As + sr * GSTR + k8;
    u16* Al1 = Al0 + 64 * GSTR;
    u16* Bl0 = Bs + sr * GSTR + k8;

    uint4 a0 = *(const uint4*)Ag0, a1 = *(const uint4*)Ag1;
    uint4 b0 = *(const uint4*)Bg0;
    for (int k0 = 0; k0 < DMODEL; k0 += 32) {
      __syncthreads();
      *(uint4*)Al0 = a0; *(uint4*)Al1 = a1;
      *(uint4*)Bl0 = b0;
      __syncthreads();
      if (k0 + 32 < DMODEL) {
        a0 = *(const uint4*)(Ag0 + k0 + 32);
        a1 = *(const uint4*)(Ag1 + k0 + 32);
        b0 = *(const uint4*)(Bg0 + k0 + 32);
      }
      bf16x8_t af[4], bfr[2];
      #pragma unroll
      for (int i = 0; i < 4; ++i)
        af[i] = *(const bf16x8_t*)(As + (wm + i * 16 + c) * FSTR + quad * 8);
      #pragma unroll
      for (int i = 0; i < 2; ++i)
        bfr[i] = *(const bf16x8_t*)(Bs + (wn + i * 16 + c) * FSTR + quad * 8);
      #pragma unroll
      for (int mt = 0; mt < 4; ++mt)
        #pragma unroll
        for (int nt = 0; nt < 2; ++nt)
          acc[mt * 2 + nt] = __builtin_amdgcn_mfma_f32_16x16x32_bf16(af[mt], bfr[nt], acc[mt * 2 + nt], 0, 0, 0);
    }
  }

  if constexpr (MODE == 0) {
    #pragma unroll
    for (int mt = 0; mt < 4; ++mt) {
      int grow0 = m0 + wm + mt * 16 + quad * 4;
      #pragma unroll
      for (int nt = 0; nt < 2; ++nt) {
        int gcol = n0 + wn + nt * 16 + c;
        #pragma unroll
        for (int r = 0; r < 4; ++r)
          C[(size_t)(grow0 + r) * DMODEL + gcol] = acc[mt * 2 + nt][r];
      }
    }
  } else {
    const int whichblk = n0 >> 10;
    if (whichblk == 2) {
      #pragma unroll
      for (int mt = 0; mt < 4; ++mt) {
        int grow0 = m0 + wm + mt * 16 + quad * 4;
        int b = grow0 >> 11, s0 = grow0 & 2047;
        #pragma unroll
        for (int nt = 0; nt < 4; ++nt) {
          int cc = (n0 + wn + nt * 16 + c) & 1023;
          int hh = cc >> 6, dk = cc & 63;
          f32x4_t v4 = acc[mt * 4 + nt];
          ushort4 o;
          o.x = f2b(v4[0]); o.y = f2b(v4[1]); o.z = f2b(v4[2]); o.w = f2b(v4[3]);
          *(ushort4*)(vt16 + (((size_t)(b * NH + hh)) * DK + dk) * S_LEN + s0) = o;
        }
      }
    } else {
      u16* tb = (w & 1) ? Bs : As;
      const int base_mw = m0 + wm;
      const int bb = base_mw >> 11, s0g = base_mw & 2047;
      const int cc = (n0 + wn) & 1023;
      const int hh = cc >> 6;
      u16* qk = (whichblk == 0 ? q16 : k16) + (((size_t)(bb * NH + hh)) * S_LEN + s0g) * DK;
      __syncthreads();
      #pragma unroll
      for (int round = 0; round < 2; ++round) {
        if ((w >> 1) == round) {
          #pragma unroll
          for (int mt = 0; mt < 4; ++mt)
            #pragma unroll
            for (int nt = 0; nt < 4; ++nt)
              #pragma unroll
              for (int r = 0; r < 4; ++r)
                tb[(mt * 16 + quad * 4 + r) * 72 + nt * 16 + c] = f2b(acc[mt * 4 + nt][r]);
          #pragma unroll
          for (int i = 0; i < 8; ++i) {
            int lrow = i * 8 + (l >> 3);
            int chk = l & 7;
            uint4 vv = *(const uint4*)(tb + lrow * 72 + chk * 8);
            *(uint4*)(qk + (size_t)lrow * DK + chk * 8) = vv;
          }
        }
        __syncthreads();
      }
    }
  }
}

// ---------------- MFMA flash attention (R5-proven, 51.7 us): 128-q blocks, KVBLK=128, XCD swizzle ----------------
// 512 threads = 8 waves = 4 q-groups (32 q) x 2 key-halves (64 keys = 2 x 32-key chunks).
// Achieved occupancy is invariant at ~32% for 16- and 32-wave/CU caps (R5/R7 evidence) -> this
// configuration is the empirical optimum of the structure family; do not re-trade staging for TLP.
#define KSTR 72    // K row stride in u16 (144 B), R3-proven conflict-free
#define VSTR 136   // V^T row stride in u16 (272 B), same %32-word class as KSTR
__global__ __launch_bounds__(512, 4) void attn_mfma_kernel(const u16* __restrict__ q,
                                                           const u16* __restrict__ k,
                                                           const u16* __restrict__ vt,
                                                           const float* __restrict__ btab,
                                                           u16* __restrict__ ctx) {
  __shared__ __align__(16) char smem[37376];
  u16*   Ks   = (u16*)smem;                   // [128][KSTR]  18432 B
  u16*   Vts  = (u16*)(smem + 18432);         // [64][VSTR]   17408 B
  float* band = (float*)(smem + 35840);       // [256]         1024 B
  float* lpx  = (float*)(smem + 36864);       // [4][32]        512 B

  const int t = threadIdx.x;
  const int w = t >> 6, l = t & 63;
  const int c32 = l & 31, h32 = l >> 5;
  const int grp = w >> 1, kh = w & 1;

  // bijective XCD swizzle: orig%8 = XCD (round-robin dispatch) -> contiguous bh-major chunk
  const int orig = blockIdx.x;                 // 0..511
  const int swz = (orig & 7) * 64 + (orig >> 3);
  const int bh = swz >> 4;                     // 0..31
  const int q0 = (swz & 15) * 128;
  const int h = bh & (NH - 1), b = bh >> 4;

  const u16* qb = q + (size_t)bh * S_LEN * DK;
  const u16* kb = k + (size_t)bh * S_LEN * DK;
  const u16* vb = vt + (size_t)bh * DK * S_LEN;
  const float* btp = btab + h * 4095 + (2047 - 127 - q0);

  // Q fragments (B operand of 32x32x16): lane holds Q[q = c32][dk = kb4*16 + h32*8 + j]
  bf16x8_t qfrag[4];
  {
    const u16* qp = qb + (size_t)(q0 + grp * 32 + c32) * DK + h32 * 8;
    qfrag[0] = *(const bf16x8_t*)(qp);
    qfrag[1] = *(const bf16x8_t*)(qp + 16);
    qfrag[2] = *(const bf16x8_t*)(qp + 32);
    qfrag[3] = *(const bf16x8_t*)(qp + 48);
  }

  float lp = 0.f;
  f32x16_t O0 = {}, O1 = {};   // O: row=q=(r&3)+8*(r>>2)+4*h32, col=dk=dh*32+c32

  // staging (512 threads, 4 x uint4 each): K 128x64, V^T 64x128
  const int ksr = t >> 2;             // 0..127
  const int ksc = (t & 3) * 8;        // 0..24
  const u16* kgp = kb + (size_t)ksr * DK + ksc;
  u16* Kl = Ks + ksr * KSTR + ksc;
  const int vsr = t >> 3;             // 0..63
  const int vsc = (t & 7) * 8;        // 0..56
  const u16* vgp = vb + (size_t)vsr * S_LEN + vsc;
  u16* Vl = Vts + vsr * VSTR + vsc;

  uint4 kr0 = *(const uint4*)kgp;
  uint4 kr1 = *(const uint4*)(kgp + 32);
  uint4 vr0 = *(const uint4*)vgp;
  uint4 vr1 = *(const uint4*)(vgp + 64);
  float br = (t < 256) ? btp[t] : 0.f;

  const int krA = (kh * 64 + c32) * KSTR + h32 * 8;           // chunk A K-frag base
  const int bndcA = 127 + kh * 64 + 4 * h32 - grp * 32 - c32; // chunk A band base

  for (int kt = 0; kt < S_LEN; kt += 128) {
    *(uint4*)Kl = kr0;        *(uint4*)(Kl + 32) = kr1;
    *(uint4*)Vl = vr0;        *(uint4*)(Vl + 64) = vr1;
    if (t < 256) band[t] = br;
    __syncthreads();
    if (kt + 128 < S_LEN) {
      kr0 = *(const uint4*)(kgp + (size_t)(kt + 128) * DK);
      kr1 = *(const uint4*)(kgp + (size_t)(kt + 128) * DK + 32);
      vr0 = *(const uint4*)(vgp + (kt + 128));
      vr1 = *(const uint4*)(vgp + (kt + 128) + 64);
      br = (t < 256) ? btp[kt + 128 + t] : 0.f;
    }
    const int D = kt - q0;
    const bool far = (D >= 256) || (D <= -256);

    // QK^T (swapped), two independent 32-key chunks
    f32x16_t sA = {}, sB = {};
    __builtin_amdgcn_s_setprio(1);
    #pragma unroll
    for (int kb4 = 0; kb4 < 4; ++kb4) {
      bf16x8_t kfA = *(const bf16x8_t*)(Ks + krA + kb4 * 16);
      sA = __builtin_amdgcn_mfma_f32_32x32x16_bf16(kfA, qfrag[kb4], sA, 0, 0, 0);
    }
    #pragma unroll
    for (int kb4 = 0; kb4 < 4; ++kb4) {
      bf16x8_t kfB = *(const bf16x8_t*)(Ks + krA + 32 * KSTR + kb4 * 16);
      sB = __builtin_amdgcn_mfma_f32_32x32x16_bf16(kfB, qfrag[kb4], sB, 0, 0, 0);
    }
    __builtin_amdgcn_s_setprio(0);

    const float bfc = band[127];

    // ---- chunk A: softmax + pack + PV ----
    {
      float p[16];
      if (far) {
        #pragma unroll
        for (int r = 0; r < 16; ++r)
          p[r] = fexp2(fmaf(sA[r], LOG2E, bfc));
      } else {
        #pragma unroll
        for (int r = 0; r < 16; ++r)
          p[r] = fexp2(fmaf(sA[r], LOG2E, band[bndcA + (r & 3) + 8 * (r >> 2)]));
      }
      #pragma unroll
      for (int r = 0; r < 16; ++r)
        lp += p[r];
      union PW { u32 wds[4]; bf16x8_t v; } pa0, pa1;
      u32 x, y;
      x = cvtpk(p[0], p[1]);   y = cvtpk(p[4], p[5]);   plswap(x, y);
      pa0.wds[0] = x; pa0.wds[2] = y;
      x = cvtpk(p[2], p[3]);   y = cvtpk(p[6], p[7]);   plswap(x, y);
      pa0.wds[1] = x; pa0.wds[3] = y;
      x = cvtpk(p[8], p[9]);   y = cvtpk(p[12], p[13]); plswap(x, y);
      pa1.wds[0] = x; pa1.wds[2] = y;
      x = cvtpk(p[10], p[11]); y = cvtpk(p[14], p[15]); plswap(x, y);
      pa1.wds[1] = x; pa1.wds[3] = y;
      __builtin_amdgcn_s_setprio(1);
      bf16x8_t vf00 = *(const bf16x8_t*)(Vts + (c32)      * VSTR + kh * 64 + h32 * 8);
      bf16x8_t vf01 = *(const bf16x8_t*)(Vts + (32 + c32) * VSTR + kh * 64 + h32 * 8);
      O0 = __builtin_amdgcn_mfma_f32_32x32x16_bf16(pa0.v, vf00, O0, 0, 0, 0);
      O1 = __builtin_amdgcn_mfma_f32_32x32x16_bf16(pa0.v, vf01, O1, 0, 0, 0);
      bf16x8_t vf10 = *(const bf16x8_t*)(Vts + (c32)      * VSTR + kh * 64 + 16 + h32 * 8);
      bf16x8_t vf11 = *(const bf16x8_t*)(Vts + (32 + c32) * VSTR + kh * 64 + 16 + h32 * 8);
      O0 = __builtin_amdgcn_mfma_f32_32x32x16_bf16(pa1.v, vf10, O0, 0, 0, 0);
      O1 = __builtin_amdgcn_mfma_f32_32x32x16_bf16(pa1.v, vf11, O1, 0, 0, 0);
      __builtin_amdgcn_s_setprio(0);
    }

    // ---- chunk B (keys +32): softmax + pack + PV ----
    {
      float p[16];
      if (far) {
        #pragma unroll
        for (int r = 0; r < 16; ++r)
          p[r] = fexp2(fmaf(sB[r], LOG2E, bfc));
      } else {
        #pragma unroll
        for (int r = 0; r < 16; ++r)
          p[r] = fexp2(fmaf(sB[r], LOG2E, band[bndcA + 32 + (r & 3) + 8 * (r >> 2)]));
      }
      #pragma unroll
      for (int r = 0; r < 16; ++r)
        lp += p[r];
      union PW { u32 wds[4]; bf16x8_t v; } pa0, pa1;
      u32 x, y;
      x = cvtpk(p[0], p[1]);   y = cvtpk(p[4], p[5]);   plswap(x, y);
      pa0.wds[0] = x; pa0.wds[2] = y;
      x = cvtpk(p[2], p[3]);   y = cvtpk(p[6], p[7]);   plswap(x, y);
      pa0.wds[1] = x; pa0.wds[3] = y;
      x = cvtpk(p[8], p[9]);   y = cvtpk(p[12], p[13]); plswap(x, y);
      pa1.wds[0] = x; pa1.wds[2] = y;
      x = cvtpk(p[10], p[11]); y = cvtpk(p[14], p[15]); plswap(x, y);
      pa1.wds[1] = x; pa1.wds[3] = y;
      __builtin_amdgcn_s_setprio(1);
      bf16x8_t vf00 = *(const bf16x8_t*)(Vts + (c32)      * VSTR + kh * 64 + 32 + h32 * 8);
      bf16x8_t vf01 = *(const bf16x8_t*)(Vts + (32 + c32) * VSTR + kh * 64 + 32 + h32 * 8);
      O0 = __builtin_amdgcn_mfma_f32_32x32x16_bf16(pa0.v, vf00, O0, 0, 0, 0);
      O1 = __builtin_amdgcn_mfma_f32_32x32x16_bf16(pa0.v, vf01, O1, 0, 0, 0);
      bf16x8_t vf10 = *(const bf16x8_t*)(Vts + (c32)      * VSTR + kh * 64 + 48 + h32 * 8);
      bf16x8_t vf11 = *(const bf16x8_t*)(Vts + (32 + c32) * VSTR + kh * 64 + 48 + h32 * 8);
      O0 = __builtin_amdgcn_mfma_f32_32x32x16_bf16(pa1.v, vf10, O0, 0, 0, 0);
      O1 = __builtin_amdgcn_mfma_f32_32x32x16_bf16(pa1.v, vf11, O1, 0, 0, 0);
      __builtin_amdgcn_s_setprio(0);
    }
    __syncthreads();   // all reads of Ks/Vts/band done before next iter's writes
  }

  // ---- epilogue: combine key-half partials; Ored aliases dead Ks/Vts region (33792 <= 35840 B) ----
  lp += __shfl_xor(lp, 32, 64);
  float (*Ored)[64][33] = (float (*)[64][33])smem;

  if (kh == 1) {
    #pragma unroll
    for (int r = 0; r < 16; ++r) {
      Ored[grp][l][r]      = O0[r];
      Ored[grp][l][16 + r] = O1[r];
    }
    if (l < 32) lpx[grp * 32 + l] = lp;
  }
  __syncthreads();
  if (kh == 0) {
    lp += lpx[grp * 32 + c32];
    float rv = 1.0f / lp;            // valid in every lane for q = c32
    #pragma unroll
    for (int r = 0; r < 16; ++r) {
      int qr = (r & 3) + 8 * (r >> 2) + 4 * h32;     // q within group
      float inv = __shfl(rv, qr, 64);
      float o0 = O0[r] + Ored[grp][l][r];
      float o1 = O1[r] + Ored[grp][l][16 + r];
      int s = q0 + grp * 32 + qr;
      u16* cp = ctx + ((size_t)(b * S_LEN + s)) * DMODEL + h * DK;
      cp[c32]      = f2b(o0 * inv);
      cp[32 + c32] = f2b(o1 * inv);
    }
  }
}

extern "C" void kernel_launch(void* const* d_in, const int* in_sizes, int n_in,
                              void* d_out, int out_size, void* d_ws, size_t ws_size,
                              hipStream_t stream) {
  const float* x   = (const float*)d_in[0];
  const float* Wq  = (const float*)d_in[1];
  const float* Wk  = (const float*)d_in[2];
  const float* Wv  = (const float*)d_in[3];
  const float* Wo  = (const float*)d_in[4];
  const float* rel = (const float*)d_in[5];
  float* out = (float*)d_out;

  char* ws = (char*)d_ws;
  size_t off = 0;
  auto carve = [&](size_t bytes) -> char* {
    char* p = ws + off;
    off += (bytes + 255) & ~(size_t)255;
    return p;
  };
  u16*   xb   = (u16*)  carve((size_t)MROWS * DMODEL * 2);       // x bf16
  u16*   Wall = (u16*)  carve((size_t)3 * DMODEL * DMODEL * 2);  // [Wq^T;Wk^T;Wv^T] bf16 [3072][1024]
  u16*   Wto  = (u16*)  carve((size_t)DMODEL * DMODEL * 2);
  u16*   qb16 = (u16*)  carve((size_t)4194304 * 2);              // [bh][s][64] bf16
  u16*   kb16 = (u16*)  carve((size_t)4194304 * 2);
  u16*   vt16 = (u16*)  carve((size_t)4194304 * 2);              // [bh][64][s] bf16
  float* btab = (float*)carve(((size_t)NH * 4095 + 256) * 4);    // +tail slack (band stage)
  u16*   ctxb = (u16*)  carve((size_t)4194304 * 2);              // [b][s][1024] bf16

  prep_kernel<<<8448, 256, 0, stream>>>(x, Wq, Wk, Wv, Wo, rel, xb, Wall, Wto, btab);

  dim3 qkvgrid(32, 24);  // M/128, 3072/128
  gemm128_kernel<1><<<qkvgrid, 256, 0, stream>>>(xb, Wall, nullptr, qb16, kb16, vt16);

  attn_mfma_kernel<<<512, 512, 0, stream>>>(qb16, kb16, vt16, btab, ctxb);

  dim3 ogrid(32, 16);    // M/128, 1024/64
  gemm128_kernel<0><<<ogrid, 256, 0, stream>>>(ctxb, Wto, out, nullptr, nullptr, nullptr);
}